// Round 4
// baseline (2898.175 us; speedup 1.0000x reference)
//
#include <hip/hip_runtime.h>
#include <math.h>

#define Dm 768
#define Tn 8
#define Nn 197
#define Sn 1576
#define MLPn 3072
#define NPn 196
#define MPAD 1664   // 13*128

typedef unsigned short u16;
typedef __bf16 bf16x8 __attribute__((ext_vector_type(8)));
typedef float f32x4 __attribute__((ext_vector_type(4)));
typedef unsigned int u32x4 __attribute__((ext_vector_type(4)));
typedef u16 u16x8 __attribute__((ext_vector_type(8)));
typedef u16 u16x4 __attribute__((ext_vector_type(4)));

__device__ inline u16 f2bf(float f) {
    union { float f; unsigned u; } v; v.f = f;
    unsigned r = v.u + 0x7fffu + ((v.u >> 16) & 1u);
    return (u16)(r >> 16);
}
__device__ inline float bf2f(u16 v) {
    union { unsigned u; float f; } x; x.u = ((unsigned)v) << 16; return x.f;
}

// ---------------- im2col: x[1,8,3,224,224] -> P[1568,768] bf16 ----------------
__global__ __launch_bounds__(256) void im2col_k(const float* __restrict__ x, u16* __restrict__ P) {
    int idx = blockIdx.x * 256 + threadIdx.x;
    if (idx >= 1568 * 768) return;
    int c = idx % 768, r = idx / 768;
    int p = r % 196, t = r / 196;
    int hp = p / 14, wp = p % 14;
    int ch = c / 256, rem = c % 256, py = rem / 16, px = rem % 16;
    P[idx] = f2bf(x[((t * 3 + ch) * 224 + hp * 16 + py) * 224 + wp * 16 + px]);
}

__global__ __launch_bounds__(256) void cvt_k(const float* __restrict__ s, u16* __restrict__ d, int n) {
    int i = blockIdx.x * 256 + threadIdx.x;
    if (i < n) d[i] = f2bf(s[i]);
}

// ---------------- ALL-layer weight transpose+convert: fp32 [K,N] -> bf16 [N,K] ----------------
// per layer: qkv 1728 tiles | proj 576 | fc1 2304 | fc2 2304 = 6912;  x12 layers
__global__ __launch_bounds__(256) void cvtT_all_k(const float* __restrict__ qw, const float* __restrict__ pw,
                                                  const float* __restrict__ f1w, const float* __restrict__ f2w,
                                                  u16* __restrict__ Wq, u16* __restrict__ Wp,
                                                  u16* __restrict__ W1, u16* __restrict__ W2) {
    __shared__ float tile[32][33];
    int layer = blockIdx.x / 6912;
    int bid = blockIdx.x % 6912;
    size_t lw = (size_t)layer * 768;
    const float* src; u16* dst; int K, N, k0, n0;
    if (bid < 1728)      { src = qw  + lw * 2304; dst = Wq + lw * 2304; K = 768;  N = 2304; int r = bid;        k0 = (r / 72) * 32; n0 = (r % 72) * 32; }
    else if (bid < 2304) { src = pw  + lw * 768;  dst = Wp + lw * 768;  K = 768;  N = 768;  int r = bid - 1728; k0 = (r / 24) * 32; n0 = (r % 24) * 32; }
    else if (bid < 4608) { src = f1w + lw * 3072; dst = W1 + lw * 3072; K = 768;  N = 3072; int r = bid - 2304; k0 = (r / 96) * 32; n0 = (r % 96) * 32; }
    else                 { src = f2w + lw * 3072; dst = W2 + lw * 3072; K = 3072; N = 768;  int r = bid - 4608; k0 = (r / 24) * 32; n0 = (r % 24) * 32; }
    int tx = threadIdx.x & 31, ty = threadIdx.x >> 5;
#pragma unroll
    for (int i = 0; i < 4; ++i) tile[ty + 8 * i][tx] = src[(size_t)(k0 + ty + 8 * i) * N + n0 + tx];
    __syncthreads();
#pragma unroll
    for (int i = 0; i < 4; ++i) dst[(size_t)(n0 + ty + 8 * i) * K + k0 + tx] = f2bf(tile[tx][ty + 8 * i]);
}

// ---------------- scramble + cls + pos -> h[1576,768] fp32 ----------------
__global__ __launch_bounds__(256) void build_h_k(const float* __restrict__ emb, const float* __restrict__ cls,
                                                 const float* __restrict__ pos, float* __restrict__ h) {
    int idx = blockIdx.x * 256 + threadIdx.x;
    if (idx >= Sn * Dm) return;
    int d = idx % Dm, s = idx / Dm;
    int t = s / Nn, r = s % Nn;
    float v;
    if (r == 0) v = cls[d];
    else {
        int f = (r - 1) * Dm + d;
        int p = f % NPn, dd = f / NPn;
        v = emb[(size_t)(t * NPn + p) * Dm + dd];
    }
    h[idx] = v + pos[r * Dm + d];
}

// ---------------- LayerNorm ----------------
template <typename OutT>
__global__ __launch_bounds__(256) void ln_k(const float* __restrict__ X, const float* __restrict__ g,
                                            const float* __restrict__ bta, OutT* __restrict__ Y) {
    int row = blockIdx.x;
    const float* x = X + (size_t)row * Dm;
    float s = 0.f, s2 = 0.f;
#pragma unroll
    for (int q = 0; q < 3; ++q) {
        float v = x[threadIdx.x + q * 256];
        s += v; s2 += v * v;
    }
#pragma unroll
    for (int off = 1; off < 64; off <<= 1) {
        s  += __shfl_xor(s,  off);
        s2 += __shfl_xor(s2, off);
    }
    __shared__ float red[8];
    int wv = threadIdx.x >> 6;
    if ((threadIdx.x & 63) == 0) { red[wv * 2] = s; red[wv * 2 + 1] = s2; }
    __syncthreads();
    s  = red[0] + red[2] + red[4] + red[6];
    s2 = red[1] + red[3] + red[5] + red[7];
    float mu  = s * (1.f / 768.f);
    float var = s2 * (1.f / 768.f) - mu * mu;
    float rstd = rsqrtf(var + 1e-5f);
#pragma unroll
    for (int q = 0; q < 3; ++q) {
        int i = threadIdx.x + q * 256;
        float v = (x[i] - mu) * rstd * g[i] + bta[i];
        if constexpr (sizeof(OutT) == 2) Y[(size_t)row * Dm + i] = f2bf(v);
        else                             Y[(size_t)row * Dm + i] = v;
    }
}

// ---------------- MFMA bf16 GEMM, fused epilogue ----------------
// BMxBN tile, 256 thr (4 waves 2x2), 16x16x32 MFMA, K-chunk 32.
// LDS chunk c <-> (row=((c>>6)<<4)+(c&15), kc=(c>>4)&3); frag read = ds_read_b128 at chunk idx
// ((wrow*F + i)*64 + lane), conflict-profile as m97.
template <int BM, int BN, bool BIAS, bool GELU_ACT, bool RESID, typename OutT>
__global__ __launch_bounds__(256) void mgemm_k(const u16* __restrict__ A, const u16* __restrict__ Bt,
                                               const float* __restrict__ bias, const float* __restrict__ resid,
                                               OutT* __restrict__ out, int M, int N, int K) {
    constexpr int FM = BM / 32, FN = BN / 32;
    constexpr int CA = BM / 64, CB = BN / 64;
    __shared__ u16 As[BM * 32];
    __shared__ u16 Bs[BN * 32];
    int tid = threadIdx.x, lane = tid & 63, w = tid >> 6;
    int wm = w & 1, wn = w >> 1;
    int quad = lane >> 4, l15 = lane & 15;
    int m0 = blockIdx.y * BM, n0 = blockIdx.x * BN;
    f32x4 acc[FM][FN] = {};
    const u16* Ap[CA];
    const u16* Bp[CB];
#pragma unroll
    for (int i = 0; i < CA; ++i) {
        int c = tid + 256 * i, row = ((c >> 6) << 4) + (c & 15), kc = (c >> 4) & 3;
        Ap[i] = A + (size_t)(m0 + row) * K + kc * 8;
    }
#pragma unroll
    for (int i = 0; i < CB; ++i) {
        int c = tid + 256 * i, row = ((c >> 6) << 4) + (c & 15), kc = (c >> 4) & 3;
        Bp[i] = Bt + (size_t)(n0 + row) * K + kc * 8;
    }
    for (int k0 = 0; k0 < K; k0 += 32) {
        u32x4 av[CA], bv[CB];
#pragma unroll
        for (int i = 0; i < CA; ++i) av[i] = *(const u32x4*)(Ap[i] + k0);
#pragma unroll
        for (int i = 0; i < CB; ++i) bv[i] = *(const u32x4*)(Bp[i] + k0);
#pragma unroll
        for (int i = 0; i < CA; ++i) *(u32x4*)(As + (size_t)(tid + 256 * i) * 8) = av[i];
#pragma unroll
        for (int i = 0; i < CB; ++i) *(u32x4*)(Bs + (size_t)(tid + 256 * i) * 8) = bv[i];
        __syncthreads();
        bf16x8 af[FM], bfr[FN];
#pragma unroll
        for (int i = 0; i < FM; ++i) af[i]  = *(const bf16x8*)(As + (((wm * FM + i) * 64 + lane) << 3));
#pragma unroll
        for (int i = 0; i < FN; ++i) bfr[i] = *(const bf16x8*)(Bs + (((wn * FN + i) * 64 + lane) << 3));
#pragma unroll
        for (int mi = 0; mi < FM; ++mi)
#pragma unroll
            for (int ni = 0; ni < FN; ++ni)
                acc[mi][ni] = __builtin_amdgcn_mfma_f32_16x16x32_bf16(af[mi], bfr[ni], acc[mi][ni], 0, 0, 0);
        __syncthreads();
    }
    // C/D 16x16: col = lane&15, row = quad*4 + reg
#pragma unroll
    for (int mi = 0; mi < FM; ++mi) {
#pragma unroll
        for (int r = 0; r < 4; ++r) {
            int gm = m0 + wm * (FM * 16) + mi * 16 + (quad << 2) + r;
            if (gm < M) {
#pragma unroll
                for (int ni = 0; ni < FN; ++ni) {
                    int gn = n0 + wn * (FN * 16) + ni * 16 + l15;
                    float v = acc[mi][ni][r];
                    if (BIAS) v += bias[gn];
                    if (GELU_ACT) v = 0.5f * v * (1.f + erff(v * 0.7071067811865476f));
                    size_t off = (size_t)gm * N + gn;
                    if (RESID) v += resid[off];
                    if constexpr (sizeof(OutT) == 2) ((u16*)out)[off] = f2bf(v);
                    else                             ((float*)out)[off] = v;
                }
            }
        }
    }
}

// ---------------- per-(head,frame) mean of V (bf16 input) ----------------
__global__ __launch_bounds__(64) void vmean_k(const u16* __restrict__ qkv, float* __restrict__ vm) {
    int g = blockIdx.x;      // g = h*8 + t
    int h = g >> 3, t = g & 7;
    int d = threadIdx.x;
    float s = 0.f;
    for (int n = 0; n < Nn; ++n)
        s += bf2f(qkv[(size_t)(t * Nn + n) * 2304 + 1536 + h * 64 + d]);
    vm[g * 64 + d] = s * (1.f / 197.f);
}

// ---------------- MFMA flash attention (verified round 3) ----------------
__global__ __launch_bounds__(256) void attn_mfma_k(const u16* __restrict__ qkv, float* __restrict__ Ou,
                                                   float* __restrict__ ml, int even, int nsplit,
                                                   int NG, int Sq) {
    __shared__ __align__(16) u16 Ks[64 * 64];
    __shared__ __align__(16) u16 Vt[64 * 64];
    __shared__ __align__(16) u16 Ps[4 * 32 * 64];
    int g = blockIdx.y;
    int h, sbase;
    if (even) { h = g >> 3; sbase = (g & 7) * Nn; } else { h = g; sbase = 0; }
    int split = blockIdx.z;
    int chunk = (Sq + nsplit - 1) / nsplit;
    int kbeg = split * chunk, kend = min(Sq, kbeg + chunk);
    int tid = threadIdx.x, lane = tid & 63, w = tid >> 6;
    int quad = lane >> 4, l15 = lane & 15;
    int q0w = blockIdx.x * 128 + w * 32;
    u16* Pw = Ps + w * 2048;

    bf16x8 aq[2][2];
#pragma unroll
    for (int mb = 0; mb < 2; ++mb) {
        int qidx = q0w + mb * 16 + l15; if (qidx >= Sq) qidx = Sq - 1;
        const u16* qp = qkv + (size_t)(sbase + qidx) * 2304 + h * 64;
#pragma unroll
        for (int ks = 0; ks < 2; ++ks)
            aq[mb][ks] = *(const bf16x8*)(qp + ks * 32 + quad * 8);
    }
    f32x4 acc_o[2][4] = {};
    float m_run[2][4], l_run[2][4];
#pragma unroll
    for (int mb = 0; mb < 2; ++mb)
#pragma unroll
        for (int r = 0; r < 4; ++r) { m_run[mb][r] = -INFINITY; l_run[mb][r] = 0.f; }

    for (int kt = kbeg; kt < kend; kt += 64) {
        int cnt = kend - kt; if (cnt > 64) cnt = 64;
        {
            int dc = tid & 7;
#pragma unroll
            for (int p = 0; p < 2; ++p) {
                int row = (tid >> 3) + 32 * p;
                u32x4 kd = {};
                if (row < cnt) kd = *(const u32x4*)(qkv + (size_t)(sbase + kt + row) * 2304 + 768 + h * 64 + dc * 8);
                *(u32x4*)(Ks + row * 64 + ((dc ^ (row & 7)) << 3)) = kd;
            }
        }
        {
            int d = (tid & 31) * 2, kc = tid >> 5;
            u16x8 lo, hi;
#pragma unroll
            for (int i = 0; i < 8; ++i) {
                int key = kc * 8 + i;
                unsigned t = 0;
                if (key < cnt) t = *(const unsigned*)(qkv + (size_t)(sbase + kt + key) * 2304 + 1536 + h * 64 + d);
                lo[i] = (u16)(t & 0xffffu); hi[i] = (u16)(t >> 16);
            }
            *(u16x8*)(Vt + d * 64 + ((kc ^ (d & 7)) << 3)) = lo;
            *(u16x8*)(Vt + (d + 1) * 64 + ((kc ^ ((d + 1) & 7)) << 3)) = hi;
        }
        __syncthreads();
        f32x4 acc_s[2][4] = {};
#pragma unroll
        for (int ni = 0; ni < 4; ++ni) {
            int key = l15 + ni * 16;
#pragma unroll
            for (int ks = 0; ks < 2; ++ks) {
                bf16x8 bk = *(const bf16x8*)(Ks + key * 64 + ((((ks << 2) + quad) ^ (key & 7)) << 3));
                acc_s[0][ni] = __builtin_amdgcn_mfma_f32_16x16x32_bf16(aq[0][ks], bk, acc_s[0][ni], 0, 0, 0);
                acc_s[1][ni] = __builtin_amdgcn_mfma_f32_16x16x32_bf16(aq[1][ks], bk, acc_s[1][ni], 0, 0, 0);
            }
        }
#pragma unroll
        for (int mb = 0; mb < 2; ++mb) {
#pragma unroll
            for (int ni = 0; ni < 4; ++ni) {
                int keyabs = kt + l15 + ni * 16;
#pragma unroll
                for (int r = 0; r < 4; ++r) {
                    float sv = acc_s[mb][ni][r] * 0.125f;
                    if (keyabs >= kend) sv = -1e30f;
                    acc_s[mb][ni][r] = sv;
                }
            }
#pragma unroll
            for (int r = 0; r < 4; ++r) {
                float mx = fmaxf(fmaxf(acc_s[mb][0][r], acc_s[mb][1][r]), fmaxf(acc_s[mb][2][r], acc_s[mb][3][r]));
                mx = fmaxf(mx, __shfl_xor(mx, 1));
                mx = fmaxf(mx, __shfl_xor(mx, 2));
                mx = fmaxf(mx, __shfl_xor(mx, 4));
                mx = fmaxf(mx, __shfl_xor(mx, 8));
                float mnew = fmaxf(m_run[mb][r], mx);
                float pv[4], ps = 0.f;
#pragma unroll
                for (int ni = 0; ni < 4; ++ni) { pv[ni] = __expf(acc_s[mb][ni][r] - mnew); ps += pv[ni]; }
                ps += __shfl_xor(ps, 1);
                ps += __shfl_xor(ps, 2);
                ps += __shfl_xor(ps, 4);
                ps += __shfl_xor(ps, 8);
                float alpha = __expf(m_run[mb][r] - mnew);
                l_run[mb][r] = l_run[mb][r] * alpha + ps;
                m_run[mb][r] = mnew;
#pragma unroll
                for (int ni = 0; ni < 4; ++ni) acc_o[mb][ni][r] *= alpha;
                int prow = mb * 16 + quad * 4 + r;
#pragma unroll
                for (int ni = 0; ni < 4; ++ni) {
                    int key = l15 + ni * 16;
                    Pw[prow * 64 + (((key >> 3) ^ (prow & 7)) << 3) + (key & 7)] = f2bf(pv[ni]);
                }
            }
        }
        bf16x8 ap[2][2];
#pragma unroll
        for (int mb = 0; mb < 2; ++mb)
#pragma unroll
            for (int ks = 0; ks < 2; ++ks)
                ap[mb][ks] = *(const bf16x8*)(Pw + (mb * 16 + l15) * 64 + ((((ks << 2) + quad) ^ (l15 & 7)) << 3));
#pragma unroll
        for (int ni = 0; ni < 4; ++ni) {
            int d = l15 + ni * 16;
#pragma unroll
            for (int ks = 0; ks < 2; ++ks) {
                bf16x8 bv = *(const bf16x8*)(Vt + d * 64 + ((((ks << 2) + quad) ^ (d & 7)) << 3));
                acc_o[0][ni] = __builtin_amdgcn_mfma_f32_16x16x32_bf16(ap[0][ks], bv, acc_o[0][ni], 0, 0, 0);
                acc_o[1][ni] = __builtin_amdgcn_mfma_f32_16x16x32_bf16(ap[1][ks], bv, acc_o[1][ni], 0, 0, 0);
            }
        }
        __syncthreads();
    }
    size_t gb = ((size_t)split * NG + g) * Sq;
#pragma unroll
    for (int mb = 0; mb < 2; ++mb)
#pragma unroll
        for (int r = 0; r < 4; ++r) {
            int q = q0w + mb * 16 + quad * 4 + r;
            if (q < Sq) {
                float* op = Ou + (gb + q) * 64;
#pragma unroll
                for (int ni = 0; ni < 4; ++ni) op[l15 + ni * 16] = acc_o[mb][ni][r];
                if (l15 == 0) {
                    ml[(gb + q) * 2]     = m_run[mb][r];
                    ml[(gb + q) * 2 + 1] = l_run[mb][r];
                }
            }
        }
}

// ---------------- combine splits (+vmean for even layers) -> ob bf16 ----------------
__global__ __launch_bounds__(256) void comb_k(const float* __restrict__ Ou, const float* __restrict__ ml,
                                              const float* __restrict__ vm, u16* __restrict__ ob,
                                              int even, int nsplit, int NG, int Sq) {
    int g = blockIdx.y;
    int q = blockIdx.x * 4 + (threadIdx.x >> 6);
    int d = threadIdx.x & 63;
    if (q >= Sq) return;
    int h, sbase;
    if (even) { h = g >> 3; sbase = (g & 7) * Nn; } else { h = g; sbase = 0; }
    float M = -INFINITY;
    for (int s = 0; s < nsplit; ++s) M = fmaxf(M, ml[(((size_t)s * NG + g) * Sq + q) * 2]);
    float num = 0.f, den = 0.f;
    for (int s = 0; s < nsplit; ++s) {
        size_t base = ((size_t)s * NG + g) * Sq + q;
        float wgt = __expf(ml[base * 2] - M);
        den += wgt * ml[base * 2 + 1];
        num += wgt * Ou[base * 64 + d];
    }
    float o = num / den;
    if (even) o += vm[g * 64 + d];
    ob[(size_t)(sbase + q) * Dm + h * 64 + d] = f2bf(o);
}

extern "C" void kernel_launch(void* const* d_in, const int* in_sizes, int n_in,
                              void* d_out, int out_size, void* d_ws, size_t ws_size,
                              hipStream_t stream) {
    (void)in_sizes; (void)n_in; (void)out_size; (void)ws_size;
    const float* x       = (const float*)d_in[0];
    const float* W_patch = (const float*)d_in[1];
    const float* b_patch = (const float*)d_in[2];
    const float* cls     = (const float*)d_in[3];
    const float* pos     = (const float*)d_in[4];
    const float* ln1_g   = (const float*)d_in[5];
    const float* ln1_b   = (const float*)d_in[6];
    const float* qkv_w   = (const float*)d_in[7];
    const float* qkv_b   = (const float*)d_in[8];
    const float* proj_w  = (const float*)d_in[9];
    const float* proj_b  = (const float*)d_in[10];
    const float* ln2_g   = (const float*)d_in[11];
    const float* ln2_b   = (const float*)d_in[12];
    const float* fc1_w   = (const float*)d_in[13];
    const float* fc1_b   = (const float*)d_in[14];
    const float* fc2_w   = (const float*)d_in[15];
    const float* fc2_b   = (const float*)d_in[16];
    const float* lnf_g   = (const float*)d_in[17];
    const float* lnf_b   = (const float*)d_in[18];

    char* base = (char*)d_ws;
    auto alloc = [&](size_t bytes) { void* p = base; base += (bytes + 255) & ~(size_t)255; return p; };
    u16*   P    = (u16*)  alloc((size_t)MPAD * 768 * 2);
    u16*   Wpa  = (u16*)  alloc((size_t)768 * 768 * 2);          // patch weight bf16 [N,K]
    u16*   Wq   = (u16*)  alloc((size_t)12 * 2304 * 768 * 2);    // all layers
    u16*   Wp   = (u16*)  alloc((size_t)12 * 768 * 768 * 2);
    u16*   W1   = (u16*)  alloc((size_t)12 * 3072 * 768 * 2);
    u16*   W2   = (u16*)  alloc((size_t)12 * 768 * 3072 * 2);
    float* emb  = (float*)alloc((size_t)1568 * 768 * 4);
    float* h    = (float*)alloc((size_t)Sn * Dm * 4);
    u16*   a    = (u16*)  alloc((size_t)MPAD * 768 * 2);
    u16*   qkvb = (u16*)  alloc((size_t)Sn * 2304 * 2);
    u16*   ob   = (u16*)  alloc((size_t)MPAD * 768 * 2);
    u16*   mb   = (u16*)  alloc((size_t)MPAD * 3072 * 2);
    float* vm   = (float*)alloc((size_t)96 * 64 * 4);
    float* Ou   = (float*)alloc((size_t)3 * 12 * Sn * 64 * 4);
    float* ml   = (float*)alloc((size_t)3 * 12 * Sn * 2 * 4);

    // ---- upfront: im2col + all weight conversions ----
    im2col_k<<<(1568 * 768 + 255) / 256, 256, 0, stream>>>(x, P);
    cvt_k<<<(768 * 768 + 255) / 256, 256, 0, stream>>>(W_patch, Wpa, 768 * 768);
    cvtT_all_k<<<12 * 6912, 256, 0, stream>>>(qkv_w, proj_w, fc1_w, fc2_w, Wq, Wp, W1, W2);

    // ---- patch embed ----
    mgemm_k<64, 64, true, false, false, float><<<dim3(12, 25), 256, 0, stream>>>(
        P, Wpa, b_patch, nullptr, emb, 1568, 768, 768);
    build_h_k<<<(Sn * Dm + 255) / 256, 256, 0, stream>>>(emb, cls, pos, h);

    for (int i = 0; i < 12; ++i) {
        ln_k<u16><<<Sn, 256, 0, stream>>>(h, ln1_g + i * Dm, ln1_b + i * Dm, a);
        mgemm_k<128, 128, true, false, false, u16><<<dim3(18, 13), 256, 0, stream>>>(
            a, Wq + (size_t)i * 2304 * 768, qkv_b + i * 2304, nullptr, qkvb, Sn, 2304, 768);
        if ((i & 1) == 0) {
            vmean_k<<<96, 64, 0, stream>>>(qkvb, vm);
            attn_mfma_k<<<dim3(2, 96, 1), 256, 0, stream>>>(qkvb, Ou, ml, 1, 1, 96, Nn);
            comb_k<<<dim3(50, 96), 256, 0, stream>>>(Ou, ml, vm, ob, 1, 1, 96, Nn);
        } else {
            attn_mfma_k<<<dim3(13, 12, 3), 256, 0, stream>>>(qkvb, Ou, ml, 0, 3, 12, Sn);
            comb_k<<<dim3(394, 12), 256, 0, stream>>>(Ou, ml, vm, ob, 0, 3, 12, Sn);
        }
        mgemm_k<64, 64, true, false, true, float><<<dim3(12, 25), 256, 0, stream>>>(
            ob, Wp + (size_t)i * 768 * 768, proj_b + i * Dm, h, h, Sn, 768, 768);
        ln_k<u16><<<Sn, 256, 0, stream>>>(h, ln2_g + i * Dm, ln2_b + i * Dm, a);
        mgemm_k<128, 128, true, true, false, u16><<<dim3(24, 13), 256, 0, stream>>>(
            a, W1 + (size_t)i * 3072 * 768, fc1_b + i * MLPn, nullptr, mb, Sn, 3072, 768);
        mgemm_k<64, 64, true, false, true, float><<<dim3(12, 25), 256, 0, stream>>>(
            mb, W2 + (size_t)i * 768 * 3072, fc2_b + i * Dm, h, h, Sn, 768, 3072);
    }
    ln_k<float><<<Sn, 256, 0, stream>>>(h, lnf_g, lnf_b, (float*)d_out);
}